// Round 7
// baseline (1491.756 us; speedup 1.0000x reference)
//
#include <hip/hip_runtime.h>
#include <stdint.h>

#define N_NODES 100000
#define F 128
#define E_EDGES 1600000
#define KARY 8
#define NPERMS 4
#define NOUT 64

typedef __attribute__((ext_vector_type(8))) short bf16x8;
typedef __attribute__((ext_vector_type(4))) float f32x4;

// ---------------- threefry2x32 (JAX-exact, 20 rounds) ----------------
__device__ __forceinline__ uint32_t rotl32(uint32_t v, int r) {
  return (v << r) | (v >> (32 - r));
}
__device__ __forceinline__ void tf2x32(uint32_t k0, uint32_t k1, uint32_t& x0, uint32_t& x1) {
  uint32_t ks2 = k0 ^ k1 ^ 0x1BD11BDAu;
  x0 += k0; x1 += k1;
  x0 += x1; x1 = rotl32(x1,13); x1 ^= x0;
  x0 += x1; x1 = rotl32(x1,15); x1 ^= x0;
  x0 += x1; x1 = rotl32(x1,26); x1 ^= x0;
  x0 += x1; x1 = rotl32(x1, 6); x1 ^= x0;
  x0 += k1; x1 += ks2 + 1u;
  x0 += x1; x1 = rotl32(x1,17); x1 ^= x0;
  x0 += x1; x1 = rotl32(x1,29); x1 ^= x0;
  x0 += x1; x1 = rotl32(x1,16); x1 ^= x0;
  x0 += x1; x1 = rotl32(x1,24); x1 ^= x0;
  x0 += ks2; x1 += k0 + 2u;
  x0 += x1; x1 = rotl32(x1,13); x1 ^= x0;
  x0 += x1; x1 = rotl32(x1,15); x1 ^= x0;
  x0 += x1; x1 = rotl32(x1,26); x1 ^= x0;
  x0 += x1; x1 = rotl32(x1, 6); x1 ^= x0;
  x0 += k0; x1 += k1 + 3u;
  x0 += x1; x1 = rotl32(x1,17); x1 ^= x0;
  x0 += x1; x1 = rotl32(x1,29); x1 ^= x0;
  x0 += x1; x1 = rotl32(x1,16); x1 ^= x0;
  x0 += x1; x1 = rotl32(x1,24); x1 ^= x0;
  x0 += k1; x1 += ks2 + 4u;
  x0 += x1; x1 = rotl32(x1,13); x1 ^= x0;
  x0 += x1; x1 = rotl32(x1,15); x1 ^= x0;
  x0 += x1; x1 = rotl32(x1,26); x1 ^= x0;
  x0 += x1; x1 = rotl32(x1, 6); x1 ^= x0;
  x0 += ks2; x1 += k0 + 5u;
}

// bf16 helpers
__device__ __forceinline__ unsigned short f2bf(float f) {  // RNE
  uint32_t u = __float_as_uint(f);
  uint32_t r = (u + 0x7FFFu + ((u >> 16) & 1u)) >> 16;
  return (unsigned short)r;
}
__device__ __forceinline__ float ubf(uint32_t u) { return __uint_as_float(u); }
// packed f32->bf16 (RNE) -- one instr for two converts
__device__ __forceinline__ uint32_t cvtpk(float lo, float hi) {
  uint32_t r;
  asm("v_cvt_pk_bf16_f32 %0, %1, %2" : "=v"(r) : "v"(lo), "v"(hi));
  return r;
}

// native transcendentals: single v_exp_f32 / v_rcp_f32.
__device__ __forceinline__ f32x4 exp2v(f32x4 x) {
  f32x4 r;
  r.x = __builtin_amdgcn_exp2f(x.x);
  r.y = __builtin_amdgcn_exp2f(x.y);
  r.z = __builtin_amdgcn_exp2f(x.z);
  r.w = __builtin_amdgcn_exp2f(x.w);
  return r;
}
__device__ __forceinline__ f32x4 rcpv(f32x4 x) {
  f32x4 r;
  r.x = __builtin_amdgcn_rcpf(x.x);
  r.y = __builtin_amdgcn_rcpf(x.y);
  r.z = __builtin_amdgcn_rcpf(x.z);
  r.w = __builtin_amdgcn_rcpf(x.w);
  return r;
}
// PRE-SCALED gate forms. i/f/o rows carry -log2(e): sigmoid(z)=rcp(1+exp2(y)).
// g rows carry +2*log2(e): tanh(z) = 1 - 2*rcp(exp2(y)+1) -- no mul at all.
__device__ __forceinline__ f32x4 sig4p(f32x4 y) {
  return rcpv(1.0f + exp2v(y));
}
__device__ __forceinline__ f32x4 tanh4p2(f32x4 y) {
  return 1.0f - 2.0f * rcpv(exp2v(y) + 1.0f);
}
// unscaled tanh, used for tanh(c_n)
__device__ __forceinline__ f32x4 tanh4(f32x4 x) {
  return 1.0f - 2.0f * rcpv(exp2v(x * 2.88539008f) + 1.0f);
}
__device__ __forceinline__ float sigf(float x) {
  return __builtin_amdgcn_rcpf(1.0f + __builtin_amdgcn_exp2f(x * -1.44269504f));
}

#define GSC -1.44269504f   // -log2(e): pre-scale for i/f/o gate rows
#define GSC_G 2.88539008f  // +2*log2(e): pre-scale for g gate rows

// ---------------- CSR build ----------------
#define HIST_BLK (E_EDGES / 256)  // 6250

// fat kernel: histogram (blocks 0..6249) + weight prep (next 256 blocks)
// NOTE: wihb/whb/bq are PRE-SCALED per gate row block (see sig4p/tanh4p2);
// wobT/bias are not.
__global__ __launch_bounds__(256) void k_hist_prepw(
    const int2* __restrict__ adj, int* __restrict__ deg,
    const float* __restrict__ w_ih, const float* __restrict__ w_hh,
    const float* __restrict__ b_ih, const float* __restrict__ b_hh,
    const float* __restrict__ weight,
    short* __restrict__ wihb, short* __restrict__ whb,
    float4* __restrict__ bq, short* __restrict__ wobT) {
  int b = blockIdx.x;
  if (b < HIST_BLK) {
    int e = b * 256 + threadIdx.x;
    atomicAdd(&deg[adj[e].x], 1);
  } else {
    int t = (b - HIST_BLK) * 256 + threadIdx.x;  // 0 .. 65535
    float sc = ((t >> 14) == 2) ? GSC_G : GSC;   // row = t>>7, gate = row>>7
    wihb[t] = (short)f2bf(w_ih[t] * sc);
    whb[t] = (short)f2bf(w_hh[t] * sc);
    if (t < 2 * F * NOUT) {
      int n = t & 63, k = t >> 6;
      wobT[n * 256 + k] = (short)f2bf(weight[k * NOUT + n]);
    }
    if (t < F)
      bq[t] = make_float4(GSC * (b_ih[t] + b_hh[t]), GSC * (b_ih[F + t] + b_hh[F + t]),
                          GSC_G * (b_ih[2 * F + t] + b_hh[2 * F + t]),
                          GSC * (b_ih[3 * F + t] + b_hh[3 * F + t]));
  }
}

// ---------- coalesced 3-phase exclusive scan ----------
__global__ __launch_bounds__(1024) void k_scanA(const int* __restrict__ deg,
                                                int* __restrict__ rpart,
                                                int* __restrict__ bsum) {
  __shared__ int s[1024];
  int tid = threadIdx.x;
  int i = blockIdx.x * 1024 + tid;
  int v = (i < N_NODES) ? deg[i] : 0;
  s[tid] = v;
  __syncthreads();
  for (int off = 1; off < 1024; off <<= 1) {
    int t = (tid >= off) ? s[tid - off] : 0;
    __syncthreads();
    s[tid] += t;
    __syncthreads();
  }
  if (i < N_NODES) rpart[i] = s[tid] - v;  // block-local exclusive
  if (tid == 1023) bsum[blockIdx.x] = s[tid];
}

__global__ __launch_bounds__(128) void k_scanB(const int* __restrict__ bsum,
                                               int* __restrict__ boff) {
  __shared__ int s[128];
  int tid = threadIdx.x;
  int v = (tid < 98) ? bsum[tid] : 0;
  s[tid] = v;
  __syncthreads();
  for (int off = 1; off < 128; off <<= 1) {
    int t = (tid >= off) ? s[tid - off] : 0;
    __syncthreads();
    s[tid] += t;
    __syncthreads();
  }
  if (tid < 98) boff[tid] = s[tid] - v;  // exclusive over block sums
}

__global__ void k_scatter(const int2* __restrict__ adj, const int* __restrict__ rpart,
                          const int* __restrict__ boff, int* __restrict__ cursor,
                          int2* __restrict__ csr) {
  int e = blockIdx.x * blockDim.x + threadIdx.x;
  if (e < E_EDGES) {
    int2 a = adj[e];
    int pos = rpart[a.x] + boff[a.x >> 10] + atomicAdd(&cursor[a.x], 1);
    csr[pos] = make_int2(a.y, e);  // (dst, edge_id)
  }
}

#define HS_LD 136  // 128 + 8 pad shorts
#define SEL_BLK ((N_NODES + 255) / 256)  // 391

// fat kernel: top-8 selection (blocks 0..390, latency/VALU-bound) overlapped
// with x-side-gates MFMA GEMM (remaining 3125 blocks, memory/MFMA-bound).
// xgq layout (UNPAIRED, R4): xgq[node*F + fi] = ushort4(i,f,g,o) for feature
// fi -- k_lstm's 8-wave split reads one 8B uint2 per (node, lane).
__global__ __launch_bounds__(256) void k_sel_xg(
    const int2* __restrict__ csr, const int* __restrict__ rpart,
    const int* __restrict__ boff,
    const int* __restrict__ deg, int* __restrict__ sel, int* __restrict__ lens,
    const float* __restrict__ feat, const short* __restrict__ wihb,
    const float4* __restrict__ bq, ushort4* __restrict__ xgq) {
  __shared__ short as_[32 * HS_LD];
  if (blockIdx.x < SEL_BLK) {
    // ---------------- selection (4 perms fused, JAX lexsort-exact) ----------
    int n = blockIdx.x * 256 + threadIdx.x;
    if (n >= N_NODES) return;
    uint32_t pk0[NPERMS], pk1[NPERMS];
#pragma unroll
    for (int p = 0; p < NPERMS; ++p) {
      uint32_t a = 0u, b = (uint32_t)p;
      tf2x32(0u, 42u, a, b);
      pk0[p] = a; pk1[p] = b;
    }
    int off = rpart[n] + boff[n >> 10], d = deg[n];
    unsigned long long key[NPERMS][KARY];
    int nbr[NPERMS][KARY];
#pragma unroll
    for (int p = 0; p < NPERMS; ++p)
#pragma unroll
      for (int i = 0; i < KARY; ++i) { key[p][i] = ~0ULL; nbr[p][i] = -1; }
    for (int e = 0; e < d; ++e) {
      int2 ent = csr[off + e];
#pragma unroll
      for (int p = 0; p < NPERMS; ++p) {
        uint32_t x0 = 0u, x1 = (uint32_t)ent.y;
        tf2x32(pk0[p], pk1[p], x0, x1);
        uint32_t bits = x0 ^ x1;
        unsigned long long k = ((unsigned long long)(bits >> 9) << 21) | (unsigned)ent.y;
        if (k < key[p][KARY - 1]) {
          key[p][KARY - 1] = k; nbr[p][KARY - 1] = ent.x;
#pragma unroll
          for (int s = KARY - 1; s >= 1; --s) {
            if (key[p][s] < key[p][s - 1]) {
              unsigned long long tk = key[p][s]; key[p][s] = key[p][s - 1]; key[p][s - 1] = tk;
              int tn = nbr[p][s]; nbr[p][s] = nbr[p][s - 1]; nbr[p][s - 1] = tn;
            }
          }
        }
      }
    }
    int L = d < KARY ? d : KARY;
    lens[n] = L;
#pragma unroll
    for (int p = 0; p < NPERMS; ++p)
#pragma unroll
      for (int t = 0; t < KARY; ++t)
        sel[((size_t)p * N_NODES + n) * KARY + t] = (t < L) ? nbr[p][t] : -1;
  } else {
    // ---------------- x-side gates via MFMA: 32 nodes/block ----------------
    const int tid = threadIdx.x;
    const int w = tid >> 6, l = tid & 63;
    const int l15 = l & 15, q = l >> 4;
    const int nb = (blockIdx.x - SEL_BLK) * 32;
#pragma unroll
    for (int i = 0; i < 4; ++i) {
      int idx = tid + i * 256;  // 1024 float4 = 32 rows x 128 cols
      int row = idx >> 5, c4 = (idx & 31) * 4;
      float4 v = *(const float4*)&feat[(size_t)(nb + row) * F + c4];
      ushort4 s;
      s.x = f2bf(v.x); s.y = f2bf(v.y); s.z = f2bf(v.z); s.w = f2bf(v.w);
      *(ushort4*)&as_[row * HS_LD + c4] = s;
    }
    __syncthreads();

    f32x4 acc[2][2][4];
#pragma unroll
    for (int mt = 0; mt < 2; ++mt)
#pragma unroll
      for (int ft = 0; ft < 2; ++ft)
#pragma unroll
        for (int g4 = 0; g4 < 4; ++g4) acc[mt][ft][g4] = (f32x4){0.f, 0.f, 0.f, 0.f};

    const short* ab = as_ + l15 * HS_LD + q * 8;
#pragma unroll
    for (int kt = 0; kt < 4; ++kt) {
      bf16x8 a0 = *(const bf16x8*)(ab + kt * 32);
      bf16x8 a1 = *(const bf16x8*)(ab + 16 * HS_LD + kt * 32);
#pragma unroll
      for (int g4 = 0; g4 < 4; ++g4)
#pragma unroll
        for (int ft = 0; ft < 2; ++ft) {
          bf16x8 b = *(const bf16x8*)(wihb + (size_t)(g4 * 128 + 16 * ft + 32 * w + l15) * F + q * 8 + kt * 32);
          acc[0][ft][g4] = __builtin_amdgcn_mfma_f32_16x16x32_bf16(a0, b, acc[0][ft][g4], 0, 0, 0);
          acc[1][ft][g4] = __builtin_amdgcn_mfma_f32_16x16x32_bf16(a1, b, acc[1][ft][g4], 0, 0, 0);
        }
    }
#pragma unroll
    for (int mt = 0; mt < 2; ++mt)
#pragma unroll
      for (int ft = 0; ft < 2; ++ft) {
        int fi = 32 * w + 16 * ft + l15;
        float4 bb = bq[fi];
#pragma unroll
        for (int r = 0; r < 4; ++r) {
          int node = nb + mt * 16 + q * 4 + r;
          ushort4 o;
          o.x = f2bf(acc[mt][ft][0][r] + bb.x);
          o.y = f2bf(acc[mt][ft][1][r] + bb.y);
          o.z = f2bf(acc[mt][ft][2][r] + bb.z);
          o.w = f2bf(acc[mt][ft][3][r] + bb.w);
          xgq[(size_t)node * F + fi] = o;  // unpaired layout
        }
      }
  }
}

// ---------------- fused LSTM via MFMA + fused head ----------------
// R7: 8-WAVE split (512 threads).  Each wave owns 16 features x 4 gates
// (64 gate-cols) for all 32 rows -> breg[4][4]=64 VGPRs, acc[2][4]=32,
// cst[2]=8: peak ~125 regs, capped at 128 by __launch_bounds__(512,4) so
// TWO blocks co-reside -> 16 waves/CU = 4 waves/SIMD (2x occupancy vs the
// 4-wave split's 256-reg pin at 2 waves/SIMD).  Body otherwise = verified
// R5 structure: same-step gathers folded into MFMA C-input, double-buffered
// hs, one barrier/step.  At t=7 the o-gate/tanh/h-write are skipped (h dead
// after last step; head uses cst only).
#define LB 8
#define OS_LD 264
__global__ __launch_bounds__(512, 4) void k_lstm(const short* __restrict__ whb,
                                                 const ushort4* __restrict__ xgq,
                                                 const int* __restrict__ sel,
                                                 const int* __restrict__ lens,
                                                 const float* __restrict__ feat,
                                                 const short* __restrict__ wobT,
                                                 const float* __restrict__ bias,
                                                 float* __restrict__ out) {
  __shared__ short hs[2][32 * HS_LD];  // 17408 B; hs[0] reused for the head
  __shared__ int sel_l[32][9];
  const int tid = threadIdx.x;
  const int w = tid >> 6;          // 0..7: wave owns features [16w, 16w+16)
  const int l = tid & 63;
  const int l15 = l & 15, q = l >> 4;
  const int nb = blockIdx.x * LB;
  const char* xgb = (const char*)xgq;
  const int fi8 = (16 * w + l15) * 8;  // byte offset of this lane's 8B quad

  if (tid < 256) {
    int m = tid >> 3, t = tid & 7;
    int node = nb + (m >> 2), p = m & 3;
    sel_l[m][t] = sel[((size_t)p * N_NODES + node) * KARY + t];
  }
  {
    int* h32 = (int*)hs;
    for (int i = tid; i < 32 * HS_LD; i += 512) h32[i] = 0;  // both buffers
  }
  uint32_t lp = 0;
#pragma unroll
  for (int i = 0; i < 8; ++i) lp |= (uint32_t)lens[nb + i] << (4 * i);

  // persistent B: breg[kt][g4] (64 VGPRs) -- this wave's 16-feature slice
  bf16x8 breg[4][4];
#pragma unroll
  for (int kt = 0; kt < 4; ++kt)
#pragma unroll
    for (int g4 = 0; g4 < 4; ++g4)
      breg[kt][g4] = *(const bf16x8*)(whb + (size_t)(g4 * 128 + 16 * w + l15) * F + q * 8 + kt * 32);

  const short* ab0 = hs[0] + l15 * HS_LD + q * 8;
  const short* ab1 = hs[1] + l15 * HS_LD + q * 8;

  f32x4 cst[2];
  cst[0] = (f32x4){0.f, 0.f, 0.f, 0.f};
  cst[1] = (f32x4){0.f, 0.f, 0.f, 0.f};

  __syncthreads();  // sel_l ready; hs zeroed

  auto lstm_step = [&](int t, const short* abase, short* hw) {
    // ---- gather this step's xg quads (8 x 8B); latency hides under unpack
    uint2 xr[2][4];  // [mt][r]: (i|f<<16, g|o<<16) for feature 16w+l15
#pragma unroll
    for (int mt = 0; mt < 2; ++mt)
#pragma unroll
      for (int r = 0; r < 4; ++r) {
        int seq = mt * 16 + q * 4 + r;
        int v = sel_l[seq][t];
        v = v < 0 ? 0 : v;
        xr[mt][r] = *(const uint2*)(xgb + (v << 10) + fi8);
      }

    // ---- unpack: x-gates become the MFMA C-input; xr dies pre-MFMA
    f32x4 acc[2][4];
#pragma unroll
    for (int mt = 0; mt < 2; ++mt)
#pragma unroll
      for (int r = 0; r < 4; ++r) {
        uint2 x = xr[mt][r];
        acc[mt][0][r] = ubf(x.x << 16);
        acc[mt][1][r] = ubf(x.x & 0xffff0000u);
        acc[mt][2][r] = ubf(x.y << 16);
        acc[mt][3][r] = ubf(x.y & 0xffff0000u);
      }

    // ---- MFMA phase: 32 MFMAs (2 mt x 4 g4 x 4 kt)
#pragma unroll
    for (int kt = 0; kt < 4; ++kt) {
      bf16x8 a0 = *(const bf16x8*)(abase + 0 * 16 * HS_LD + kt * 32);
      bf16x8 a1 = *(const bf16x8*)(abase + 1 * 16 * HS_LD + kt * 32);
#pragma unroll
      for (int g4 = 0; g4 < 4; ++g4) {
        acc[0][g4] = __builtin_amdgcn_mfma_f32_16x16x32_bf16(a0, breg[kt][g4], acc[0][g4], 0, 0, 0);
        acc[1][g4] = __builtin_amdgcn_mfma_f32_16x16x32_bf16(a1, breg[kt][g4], acc[1][g4], 0, 0, 0);
      }
    }
    // NO mid barrier: epilogue writes go to the OTHER buffer (hw).

    // ---- epilogue: acc holds full gate pre-activations for this slice
#pragma unroll
    for (int mt = 0; mt < 2; ++mt) {
      int len = (lp >> (4 * (mt * 4 + q))) & 15;
      bool live = t < len;
      f32x4 ii = sig4p(acc[mt][0]);
      f32x4 ff = sig4p(acc[mt][1]);
      f32x4 gg = tanh4p2(acc[mt][2]);
      f32x4 cn = ff * cst[mt] + ii * gg;
      if (live) {
        cst[mt] = cn;
        if (t < KARY - 1) {  // h dead after last step (head uses cst only)
          f32x4 oo = sig4p(acc[mt][3]);
          f32x4 hh = oo * tanh4(cn);
          int base = (mt * 16 + q * 4) * HS_LD + 16 * w + l15;
          uint32_t p01 = cvtpk(hh[0], hh[1]);
          uint32_t p23 = cvtpk(hh[2], hh[3]);
          hw[base + 0 * HS_LD] = (short)p01;
          hw[base + 1 * HS_LD] = (short)(p01 >> 16);
          hw[base + 2 * HS_LD] = (short)p23;
          hw[base + 3 * HS_LD] = (short)(p23 >> 16);
        }
      }
    }
    __syncthreads();  // writes(t) visible before reads(t+1); ONE barrier/step
  };

  for (int tt = 0; tt < KARY; tt += 2) {
    lstm_step(tt, ab0, hs[1]);
    lstm_step(tt + 1, ab1, hs[0]);
  }

  // ================= fused head: out[8][64] = sig([feat|hn]@W + b) =========
  short* as2 = hs[0];  // reinterpret as [16][OS_LD]; 16*264*2 = 8448 B fits

  // stage hn (from cst) into cols 128..255 of rows 0..7 (all 8 waves)
#pragma unroll
  for (int mt = 0; mt < 2; ++mt) {
    f32x4 cc = cst[mt];
    float hv = (cc.x + cc.y + cc.z + cc.w) * 0.25f;
    as2[(mt * 4 + q) * OS_LD + 128 + 16 * w + l15] = (short)f2bf(hv);
  }
  // stage feat bf16 into cols 0..127 of rows 0..7 (8x128 = 256 float4)
  if (tid < 256) {
    int row = tid >> 5, c4 = (tid & 31) * 4;
    float4 v = *(const float4*)&feat[(size_t)(nb + row) * F + c4];
    ushort4 s;
    s.x = f2bf(v.x); s.y = f2bf(v.y); s.z = f2bf(v.z); s.w = f2bf(v.w);
    *(ushort4*)&as2[row * OS_LD + c4] = s;
  }
  float bb = (w < 4) ? bias[16 * w + l15] : 0.f;
  __syncthreads();

  // waves 0-3 compute out cols [16w,16w+16): 8 MFMA over K=256
  if (w < 4) {
    f32x4 oacc = (f32x4){0.f, 0.f, 0.f, 0.f};
    const short* ab2 = as2 + l15 * OS_LD + q * 8;
#pragma unroll
    for (int kt = 0; kt < 8; ++kt) {
      bf16x8 a = *(const bf16x8*)(ab2 + kt * 32);  // rows 8-15 garbage, discarded
      bf16x8 b = *(const bf16x8*)(wobT + (size_t)(16 * w + l15) * 256 + q * 8 + kt * 32);
      oacc = __builtin_amdgcn_mfma_f32_16x16x32_bf16(a, b, oacc, 0, 0, 0);
    }
    if (q < 2) {  // C rows q*4+r in 0..7 are the valid nodes
#pragma unroll
      for (int r = 0; r < 4; ++r) {
        int node = nb + q * 4 + r;
        out[(size_t)node * NOUT + 16 * w + l15] = sigf(oacc[r] + bb);
      }
    }
  }
}

extern "C" void kernel_launch(void* const* d_in, const int* in_sizes, int n_in,
                              void* d_out, int out_size, void* d_ws, size_t ws_size,
                              hipStream_t stream) {
  const float* feat = (const float*)d_in[0];
  const int2* adj = (const int2*)d_in[1];
  const float* w_ih = (const float*)d_in[2];
  const float* w_hh = (const float*)d_in[3];
  const float* b_ih = (const float*)d_in[4];
  const float* b_hh = (const float*)d_in[5];
  const float* weight = (const float*)d_in[6];
  const float* bias = (const float*)d_in[7];
  float* out = (float*)d_out;

  size_t off = 0;
  auto take = [&](size_t bytes) -> void* {
    void* p = (char*)d_ws + off;
    off += (bytes + 255) & ~(size_t)255;
    return p;
  };
  int* deg = (int*)take((size_t)N_NODES * 4);
  int* rpart = (int*)take((size_t)N_NODES * 4);
  int* cursor = (int*)take((size_t)N_NODES * 4);
  int2* csr = (int2*)take((size_t)E_EDGES * 8);
  int* sel = (int*)take((size_t)NPERMS * N_NODES * KARY * 4);
  int* lens = (int*)take((size_t)N_NODES * 4);
  short* wihb = (short*)take((size_t)4 * F * F * 2);
  short* whb = (short*)take((size_t)4 * F * F * 2);
  short* wobT = (short*)take((size_t)NOUT * 2 * F * 2);
  float4* bq = (float4*)take((size_t)F * 16);
  ushort4* xgq = (ushort4*)take((size_t)N_NODES * F * 8);
  int* bsum = (int*)take(128 * 4);
  int* boff = (int*)take(128 * 4);
  (void)ws_size; (void)in_sizes; (void)n_in; (void)out_size;

  hipMemsetAsync(deg, 0, (size_t)N_NODES * 4, stream);
  hipMemsetAsync(cursor, 0, (size_t)N_NODES * 4, stream);

  k_hist_prepw<<<HIST_BLK + 256, 256, 0, stream>>>(adj, deg, w_ih, w_hh, b_ih, b_hh,
                                                   weight, wihb, whb, bq, wobT);
  k_scanA<<<98, 1024, 0, stream>>>(deg, rpart, bsum);
  k_scanB<<<1, 128, 0, stream>>>(bsum, boff);
  k_scatter<<<(E_EDGES + 255) / 256, 256, 0, stream>>>(adj, rpart, boff, cursor, csr);
  k_sel_xg<<<SEL_BLK + N_NODES / 32, 256, 0, stream>>>(csr, rpart, boff, deg, sel, lens,
                                                       feat, wihb, bq, xgq);
  k_lstm<<<N_NODES / LB, 512, 0, stream>>>(whb, xgq, sel, lens, feat, wobT, bias, out);
}

// Round 8
// 1355.328 us; speedup vs baseline: 1.1007x; 1.1007x over previous
//
#include <hip/hip_runtime.h>
#include <stdint.h>

#define N_NODES 100000
#define F 128
#define E_EDGES 1600000
#define KARY 8
#define NPERMS 4
#define NOUT 64

typedef __attribute__((ext_vector_type(8))) short bf16x8;
typedef __attribute__((ext_vector_type(4))) float f32x4;

// ---------------- threefry2x32 (JAX-exact, 20 rounds) ----------------
__device__ __forceinline__ uint32_t rotl32(uint32_t v, int r) {
  return (v << r) | (v >> (32 - r));
}
__device__ __forceinline__ void tf2x32(uint32_t k0, uint32_t k1, uint32_t& x0, uint32_t& x1) {
  uint32_t ks2 = k0 ^ k1 ^ 0x1BD11BDAu;
  x0 += k0; x1 += k1;
  x0 += x1; x1 = rotl32(x1,13); x1 ^= x0;
  x0 += x1; x1 = rotl32(x1,15); x1 ^= x0;
  x0 += x1; x1 = rotl32(x1,26); x1 ^= x0;
  x0 += x1; x1 = rotl32(x1, 6); x1 ^= x0;
  x0 += k1; x1 += ks2 + 1u;
  x0 += x1; x1 = rotl32(x1,17); x1 ^= x0;
  x0 += x1; x1 = rotl32(x1,29); x1 ^= x0;
  x0 += x1; x1 = rotl32(x1,16); x1 ^= x0;
  x0 += x1; x1 = rotl32(x1,24); x1 ^= x0;
  x0 += ks2; x1 += k0 + 2u;
  x0 += x1; x1 = rotl32(x1,13); x1 ^= x0;
  x0 += x1; x1 = rotl32(x1,15); x1 ^= x0;
  x0 += x1; x1 = rotl32(x1,26); x1 ^= x0;
  x0 += x1; x1 = rotl32(x1, 6); x1 ^= x0;
  x0 += k0; x1 += k1 + 3u;
  x0 += x1; x1 = rotl32(x1,17); x1 ^= x0;
  x0 += x1; x1 = rotl32(x1,29); x1 ^= x0;
  x0 += x1; x1 = rotl32(x1,16); x1 ^= x0;
  x0 += x1; x1 = rotl32(x1,24); x1 ^= x0;
  x0 += k1; x1 += ks2 + 4u;
  x0 += x1; x1 = rotl32(x1,13); x1 ^= x0;
  x0 += x1; x1 = rotl32(x1,15); x1 ^= x0;
  x0 += x1; x1 = rotl32(x1,26); x1 ^= x0;
  x0 += x1; x1 = rotl32(x1, 6); x1 ^= x0;
  x0 += ks2; x1 += k0 + 5u;
}

// bf16 helpers
__device__ __forceinline__ unsigned short f2bf(float f) {  // RNE
  uint32_t u = __float_as_uint(f);
  uint32_t r = (u + 0x7FFFu + ((u >> 16) & 1u)) >> 16;
  return (unsigned short)r;
}
__device__ __forceinline__ float ubf(uint32_t u) { return __uint_as_float(u); }
// packed f32->bf16 (RNE) -- one instr for two converts
__device__ __forceinline__ uint32_t cvtpk(float lo, float hi) {
  uint32_t r;
  asm("v_cvt_pk_bf16_f32 %0, %1, %2" : "=v"(r) : "v"(lo), "v"(hi));
  return r;
}

// native transcendentals: single v_exp_f32 / v_rcp_f32.
__device__ __forceinline__ f32x4 exp2v(f32x4 x) {
  f32x4 r;
  r.x = __builtin_amdgcn_exp2f(x.x);
  r.y = __builtin_amdgcn_exp2f(x.y);
  r.z = __builtin_amdgcn_exp2f(x.z);
  r.w = __builtin_amdgcn_exp2f(x.w);
  return r;
}
__device__ __forceinline__ f32x4 rcpv(f32x4 x) {
  f32x4 r;
  r.x = __builtin_amdgcn_rcpf(x.x);
  r.y = __builtin_amdgcn_rcpf(x.y);
  r.z = __builtin_amdgcn_rcpf(x.z);
  r.w = __builtin_amdgcn_rcpf(x.w);
  return r;
}
// PRE-SCALED gate forms. i/f/o rows carry -log2(e): sigmoid(z)=rcp(1+exp2(y)).
// g rows carry +2*log2(e): tanh(z) = 1 - 2*rcp(exp2(y)+1) -- no mul at all.
__device__ __forceinline__ f32x4 sig4p(f32x4 y) {
  return rcpv(1.0f + exp2v(y));
}
__device__ __forceinline__ f32x4 tanh4p2(f32x4 y) {
  return 1.0f - 2.0f * rcpv(exp2v(y) + 1.0f);
}
// unscaled tanh, used for tanh(c_n)
__device__ __forceinline__ f32x4 tanh4(f32x4 x) {
  return 1.0f - 2.0f * rcpv(exp2v(x * 2.88539008f) + 1.0f);
}
__device__ __forceinline__ float sigf(float x) {
  return __builtin_amdgcn_rcpf(1.0f + __builtin_amdgcn_exp2f(x * -1.44269504f));
}

#define GSC -1.44269504f   // -log2(e): pre-scale for i/f/o gate rows
#define GSC_G 2.88539008f  // +2*log2(e): pre-scale for g gate rows

// ---------------- CSR build ----------------
#define HIST_BLK (E_EDGES / 256)  // 6250

// fat kernel: histogram (blocks 0..6249) + weight prep (next 256 blocks)
// NOTE: wihb/whb/bq are PRE-SCALED per gate row block (see sig4p/tanh4p2);
// wobT/bias are not.
__global__ __launch_bounds__(256) void k_hist_prepw(
    const int2* __restrict__ adj, int* __restrict__ deg,
    const float* __restrict__ w_ih, const float* __restrict__ w_hh,
    const float* __restrict__ b_ih, const float* __restrict__ b_hh,
    const float* __restrict__ weight,
    short* __restrict__ wihb, short* __restrict__ whb,
    float4* __restrict__ bq, short* __restrict__ wobT) {
  int b = blockIdx.x;
  if (b < HIST_BLK) {
    int e = b * 256 + threadIdx.x;
    atomicAdd(&deg[adj[e].x], 1);
  } else {
    int t = (b - HIST_BLK) * 256 + threadIdx.x;  // 0 .. 65535
    float sc = ((t >> 14) == 2) ? GSC_G : GSC;   // row = t>>7, gate = row>>7
    wihb[t] = (short)f2bf(w_ih[t] * sc);
    whb[t] = (short)f2bf(w_hh[t] * sc);
    if (t < 2 * F * NOUT) {
      int n = t & 63, k = t >> 6;
      wobT[n * 256 + k] = (short)f2bf(weight[k * NOUT + n]);
    }
    if (t < F)
      bq[t] = make_float4(GSC * (b_ih[t] + b_hh[t]), GSC * (b_ih[F + t] + b_hh[F + t]),
                          GSC_G * (b_ih[2 * F + t] + b_hh[2 * F + t]),
                          GSC * (b_ih[3 * F + t] + b_hh[3 * F + t]));
  }
}

// ---------- coalesced 3-phase exclusive scan ----------
__global__ __launch_bounds__(1024) void k_scanA(const int* __restrict__ deg,
                                                int* __restrict__ rpart,
                                                int* __restrict__ bsum) {
  __shared__ int s[1024];
  int tid = threadIdx.x;
  int i = blockIdx.x * 1024 + tid;
  int v = (i < N_NODES) ? deg[i] : 0;
  s[tid] = v;
  __syncthreads();
  for (int off = 1; off < 1024; off <<= 1) {
    int t = (tid >= off) ? s[tid - off] : 0;
    __syncthreads();
    s[tid] += t;
    __syncthreads();
  }
  if (i < N_NODES) rpart[i] = s[tid] - v;  // block-local exclusive
  if (tid == 1023) bsum[blockIdx.x] = s[tid];
}

__global__ __launch_bounds__(128) void k_scanB(const int* __restrict__ bsum,
                                               int* __restrict__ boff) {
  __shared__ int s[128];
  int tid = threadIdx.x;
  int v = (tid < 98) ? bsum[tid] : 0;
  s[tid] = v;
  __syncthreads();
  for (int off = 1; off < 128; off <<= 1) {
    int t = (tid >= off) ? s[tid - off] : 0;
    __syncthreads();
    s[tid] += t;
    __syncthreads();
  }
  if (tid < 98) boff[tid] = s[tid] - v;  // exclusive over block sums
}

__global__ void k_scatter(const int2* __restrict__ adj, const int* __restrict__ rpart,
                          const int* __restrict__ boff, int* __restrict__ cursor,
                          int2* __restrict__ csr) {
  int e = blockIdx.x * blockDim.x + threadIdx.x;
  if (e < E_EDGES) {
    int2 a = adj[e];
    int pos = rpart[a.x] + boff[a.x >> 10] + atomicAdd(&cursor[a.x], 1);
    csr[pos] = make_int2(a.y, e);  // (dst, edge_id)
  }
}

#define HS_LD 136  // 128 + 8 pad shorts
#define SEL_BLK ((N_NODES + 255) / 256)  // 391

// fat kernel: top-8 selection (blocks 0..390, latency/VALU-bound) overlapped
// with x-side-gates MFMA GEMM (remaining 3125 blocks, memory/MFMA-bound).
// xgq layout (UNPAIRED): xgq[node*F + fi] = ushort4(i,f,g,o) for feature fi.
__global__ __launch_bounds__(256) void k_sel_xg(
    const int2* __restrict__ csr, const int* __restrict__ rpart,
    const int* __restrict__ boff,
    const int* __restrict__ deg, int* __restrict__ sel, int* __restrict__ lens,
    const float* __restrict__ feat, const short* __restrict__ wihb,
    const float4* __restrict__ bq, ushort4* __restrict__ xgq) {
  __shared__ short as_[32 * HS_LD];
  if (blockIdx.x < SEL_BLK) {
    // ---------------- selection (4 perms fused, JAX lexsort-exact) ----------
    int n = blockIdx.x * 256 + threadIdx.x;
    if (n >= N_NODES) return;
    uint32_t pk0[NPERMS], pk1[NPERMS];
#pragma unroll
    for (int p = 0; p < NPERMS; ++p) {
      uint32_t a = 0u, b = (uint32_t)p;
      tf2x32(0u, 42u, a, b);
      pk0[p] = a; pk1[p] = b;
    }
    int off = rpart[n] + boff[n >> 10], d = deg[n];
    unsigned long long key[NPERMS][KARY];
    int nbr[NPERMS][KARY];
#pragma unroll
    for (int p = 0; p < NPERMS; ++p)
#pragma unroll
      for (int i = 0; i < KARY; ++i) { key[p][i] = ~0ULL; nbr[p][i] = -1; }
    for (int e = 0; e < d; ++e) {
      int2 ent = csr[off + e];
#pragma unroll
      for (int p = 0; p < NPERMS; ++p) {
        uint32_t x0 = 0u, x1 = (uint32_t)ent.y;
        tf2x32(pk0[p], pk1[p], x0, x1);
        uint32_t bits = x0 ^ x1;
        unsigned long long k = ((unsigned long long)(bits >> 9) << 21) | (unsigned)ent.y;
        if (k < key[p][KARY - 1]) {
          key[p][KARY - 1] = k; nbr[p][KARY - 1] = ent.x;
#pragma unroll
          for (int s = KARY - 1; s >= 1; --s) {
            if (key[p][s] < key[p][s - 1]) {
              unsigned long long tk = key[p][s]; key[p][s] = key[p][s - 1]; key[p][s - 1] = tk;
              int tn = nbr[p][s]; nbr[p][s] = nbr[p][s - 1]; nbr[p][s - 1] = tn;
            }
          }
        }
      }
    }
    int L = d < KARY ? d : KARY;
    lens[n] = L;
#pragma unroll
    for (int p = 0; p < NPERMS; ++p)
#pragma unroll
      for (int t = 0; t < KARY; ++t)
        sel[((size_t)p * N_NODES + n) * KARY + t] = (t < L) ? nbr[p][t] : -1;
  } else {
    // ---------------- x-side gates via MFMA: 32 nodes/block ----------------
    const int tid = threadIdx.x;
    const int w = tid >> 6, l = tid & 63;
    const int l15 = l & 15, q = l >> 4;
    const int nb = (blockIdx.x - SEL_BLK) * 32;
#pragma unroll
    for (int i = 0; i < 4; ++i) {
      int idx = tid + i * 256;  // 1024 float4 = 32 rows x 128 cols
      int row = idx >> 5, c4 = (idx & 31) * 4;
      float4 v = *(const float4*)&feat[(size_t)(nb + row) * F + c4];
      ushort4 s;
      s.x = f2bf(v.x); s.y = f2bf(v.y); s.z = f2bf(v.z); s.w = f2bf(v.w);
      *(ushort4*)&as_[row * HS_LD + c4] = s;
    }
    __syncthreads();

    f32x4 acc[2][2][4];
#pragma unroll
    for (int mt = 0; mt < 2; ++mt)
#pragma unroll
      for (int ft = 0; ft < 2; ++ft)
#pragma unroll
        for (int g4 = 0; g4 < 4; ++g4) acc[mt][ft][g4] = (f32x4){0.f, 0.f, 0.f, 0.f};

    const short* ab = as_ + l15 * HS_LD + q * 8;
#pragma unroll
    for (int kt = 0; kt < 4; ++kt) {
      bf16x8 a0 = *(const bf16x8*)(ab + kt * 32);
      bf16x8 a1 = *(const bf16x8*)(ab + 16 * HS_LD + kt * 32);
#pragma unroll
      for (int g4 = 0; g4 < 4; ++g4)
#pragma unroll
        for (int ft = 0; ft < 2; ++ft) {
          bf16x8 b = *(const bf16x8*)(wihb + (size_t)(g4 * 128 + 16 * ft + 32 * w + l15) * F + q * 8 + kt * 32);
          acc[0][ft][g4] = __builtin_amdgcn_mfma_f32_16x16x32_bf16(a0, b, acc[0][ft][g4], 0, 0, 0);
          acc[1][ft][g4] = __builtin_amdgcn_mfma_f32_16x16x32_bf16(a1, b, acc[1][ft][g4], 0, 0, 0);
        }
    }
#pragma unroll
    for (int mt = 0; mt < 2; ++mt)
#pragma unroll
      for (int ft = 0; ft < 2; ++ft) {
        int fi = 32 * w + 16 * ft + l15;
        float4 bb = bq[fi];
#pragma unroll
        for (int r = 0; r < 4; ++r) {
          int node = nb + mt * 16 + q * 4 + r;
          ushort4 o;
          o.x = f2bf(acc[mt][ft][0][r] + bb.x);
          o.y = f2bf(acc[mt][ft][1][r] + bb.y);
          o.z = f2bf(acc[mt][ft][2][r] + bb.z);
          o.w = f2bf(acc[mt][ft][3][r] + bb.w);
          xgq[(size_t)node * F + fi] = o;  // unpaired layout
        }
      }
  }
}

// ---------------- fused LSTM via MFMA + fused head ----------------
// R8: the 8-wave split WITHOUT the forced register cap.  R7's regression was
// a forced spill: __launch_bounds__(512,4) capped at 128 regs, natural
// footprint (64 breg VGPR + 32 acc AGPR + xr + addressing, unified file)
// exceeded it -> deterministic 675MB scratch WRITE.  With (512,2) the
// compiler allocates naturally (~110-125); if <=128 total, HW co-resides
// TWO independent 8-wave blocks/CU = 4 waves/SIMD with PHASE DIVERSITY
// (R5's stall is phase-locked barrier convergence -- co-resident waves of
// the same block stall together).  Body = verified R5 structure + t=7
// o-gate/h-write skip (verified in R7).
#define LB 8
#define OS_LD 264
__global__ __launch_bounds__(512, 2) void k_lstm(const short* __restrict__ whb,
                                                 const ushort4* __restrict__ xgq,
                                                 const int* __restrict__ sel,
                                                 const int* __restrict__ lens,
                                                 const float* __restrict__ feat,
                                                 const short* __restrict__ wobT,
                                                 const float* __restrict__ bias,
                                                 float* __restrict__ out) {
  __shared__ short hs[2][32 * HS_LD];  // 17408 B; hs[0] reused for the head
  __shared__ int sel_l[32][9];
  const int tid = threadIdx.x;
  const int w = tid >> 6;          // 0..7: wave owns features [16w, 16w+16)
  const int l = tid & 63;
  const int l15 = l & 15, q = l >> 4;
  const int nb = blockIdx.x * LB;
  const char* xgb = (const char*)xgq;
  const int fi8 = (16 * w + l15) * 8;  // byte offset of this lane's 8B quad

  if (tid < 256) {
    int m = tid >> 3, t = tid & 7;
    int node = nb + (m >> 2), p = m & 3;
    sel_l[m][t] = sel[((size_t)p * N_NODES + node) * KARY + t];
  }
  {
    int* h32 = (int*)hs;
    for (int i = tid; i < 32 * HS_LD; i += 512) h32[i] = 0;  // both buffers
  }
  uint32_t lp = 0;
#pragma unroll
  for (int i = 0; i < 8; ++i) lp |= (uint32_t)lens[nb + i] << (4 * i);

  // persistent B: breg[kt][g4] (64 VGPRs) -- this wave's 16-feature slice
  bf16x8 breg[4][4];
#pragma unroll
  for (int kt = 0; kt < 4; ++kt)
#pragma unroll
    for (int g4 = 0; g4 < 4; ++g4)
      breg[kt][g4] = *(const bf16x8*)(whb + (size_t)(g4 * 128 + 16 * w + l15) * F + q * 8 + kt * 32);

  const short* ab0 = hs[0] + l15 * HS_LD + q * 8;
  const short* ab1 = hs[1] + l15 * HS_LD + q * 8;

  f32x4 cst[2];
  cst[0] = (f32x4){0.f, 0.f, 0.f, 0.f};
  cst[1] = (f32x4){0.f, 0.f, 0.f, 0.f};

  __syncthreads();  // sel_l ready; hs zeroed

  auto lstm_step = [&](int t, const short* abase, short* hw) {
    // ---- gather this step's xg quads (8 x 8B); hoistable by the compiler
    uint2 xr[2][4];  // [mt][r]: (i|f<<16, g|o<<16) for feature 16w+l15
#pragma unroll
    for (int mt = 0; mt < 2; ++mt)
#pragma unroll
      for (int r = 0; r < 4; ++r) {
        int seq = mt * 16 + q * 4 + r;
        int v = sel_l[seq][t];
        v = v < 0 ? 0 : v;
        xr[mt][r] = *(const uint2*)(xgb + (v << 10) + fi8);
      }

    // ---- unpack: x-gates become the MFMA C-input; xr dies pre-MFMA
    f32x4 acc[2][4];
#pragma unroll
    for (int mt = 0; mt < 2; ++mt)
#pragma unroll
      for (int r = 0; r < 4; ++r) {
        uint2 x = xr[mt][r];
        acc[mt][0][r] = ubf(x.x << 16);
        acc[mt][1][r] = ubf(x.x & 0xffff0000u);
        acc[mt][2][r] = ubf(x.y << 16);
        acc[mt][3][r] = ubf(x.y & 0xffff0000u);
      }

    // ---- MFMA phase: 32 MFMAs (2 mt x 4 g4 x 4 kt)
#pragma unroll
    for (int kt = 0; kt < 4; ++kt) {
      bf16x8 a0 = *(const bf16x8*)(abase + 0 * 16 * HS_LD + kt * 32);
      bf16x8 a1 = *(const bf16x8*)(abase + 1 * 16 * HS_LD + kt * 32);
#pragma unroll
      for (int g4 = 0; g4 < 4; ++g4) {
        acc[0][g4] = __builtin_amdgcn_mfma_f32_16x16x32_bf16(a0, breg[kt][g4], acc[0][g4], 0, 0, 0);
        acc[1][g4] = __builtin_amdgcn_mfma_f32_16x16x32_bf16(a1, breg[kt][g4], acc[1][g4], 0, 0, 0);
      }
    }
    // NO mid barrier: epilogue writes go to the OTHER buffer (hw).

    // ---- epilogue: acc holds full gate pre-activations for this slice
#pragma unroll
    for (int mt = 0; mt < 2; ++mt) {
      int len = (lp >> (4 * (mt * 4 + q))) & 15;
      bool live = t < len;
      f32x4 ii = sig4p(acc[mt][0]);
      f32x4 ff = sig4p(acc[mt][1]);
      f32x4 gg = tanh4p2(acc[mt][2]);
      f32x4 cn = ff * cst[mt] + ii * gg;
      if (live) {
        cst[mt] = cn;
        if (t < KARY - 1) {  // h dead after last step (head uses cst only)
          f32x4 oo = sig4p(acc[mt][3]);
          f32x4 hh = oo * tanh4(cn);
          int base = (mt * 16 + q * 4) * HS_LD + 16 * w + l15;
          uint32_t p01 = cvtpk(hh[0], hh[1]);
          uint32_t p23 = cvtpk(hh[2], hh[3]);
          hw[base + 0 * HS_LD] = (short)p01;
          hw[base + 1 * HS_LD] = (short)(p01 >> 16);
          hw[base + 2 * HS_LD] = (short)p23;
          hw[base + 3 * HS_LD] = (short)(p23 >> 16);
        }
      }
    }
    __syncthreads();  // writes(t) visible before reads(t+1); ONE barrier/step
  };

  for (int tt = 0; tt < KARY; tt += 2) {
    lstm_step(tt, ab0, hs[1]);
    lstm_step(tt + 1, ab1, hs[0]);
  }

  // ================= fused head: out[8][64] = sig([feat|hn]@W + b) =========
  short* as2 = hs[0];  // reinterpret as [16][OS_LD]; 16*264*2 = 8448 B fits

  // stage hn (from cst) into cols 128..255 of rows 0..7 (all 8 waves)
#pragma unroll
  for (int mt = 0; mt < 2; ++mt) {
    f32x4 cc = cst[mt];
    float hv = (cc.x + cc.y + cc.z + cc.w) * 0.25f;
    as2[(mt * 4 + q) * OS_LD + 128 + 16 * w + l15] = (short)f2bf(hv);
  }
  // stage feat bf16 into cols 0..127 of rows 0..7 (8x128 = 256 float4)
  if (tid < 256) {
    int row = tid >> 5, c4 = (tid & 31) * 4;
    float4 v = *(const float4*)&feat[(size_t)(nb + row) * F + c4];
    ushort4 s;
    s.x = f2bf(v.x); s.y = f2bf(v.y); s.z = f2bf(v.z); s.w = f2bf(v.w);
    *(ushort4*)&as2[row * OS_LD + c4] = s;
  }
  float bb = (w < 4) ? bias[16 * w + l15] : 0.f;
  __syncthreads();

  // waves 0-3 compute out cols [16w,16w+16): 8 MFMA over K=256
  if (w < 4) {
    f32x4 oacc = (f32x4){0.f, 0.f, 0.f, 0.f};
    const short* ab2 = as2 + l15 * OS_LD + q * 8;
#pragma unroll
    for (int kt = 0; kt < 8; ++kt) {
      bf16x8 a = *(const bf16x8*)(ab2 + kt * 32);  // rows 8-15 garbage, discarded
      bf16x8 b = *(const bf16x8*)(wobT + (size_t)(16 * w + l15) * 256 + q * 8 + kt * 32);
      oacc = __builtin_amdgcn_mfma_f32_16x16x32_bf16(a, b, oacc, 0, 0, 0);
    }
    if (q < 2) {  // C rows q*4+r in 0..7 are the valid nodes
#pragma unroll
      for (int r = 0; r < 4; ++r) {
        int node = nb + q * 4 + r;
        out[(size_t)node * NOUT + 16 * w + l15] = sigf(oacc[r] + bb);
      }
    }
  }
}

extern "C" void kernel_launch(void* const* d_in, const int* in_sizes, int n_in,
                              void* d_out, int out_size, void* d_ws, size_t ws_size,
                              hipStream_t stream) {
  const float* feat = (const float*)d_in[0];
  const int2* adj = (const int2*)d_in[1];
  const float* w_ih = (const float*)d_in[2];
  const float* w_hh = (const float*)d_in[3];
  const float* b_ih = (const float*)d_in[4];
  const float* b_hh = (const float*)d_in[5];
  const float* weight = (const float*)d_in[6];
  const float* bias = (const float*)d_in[7];
  float* out = (float*)d_out;

  size_t off = 0;
  auto take = [&](size_t bytes) -> void* {
    void* p = (char*)d_ws + off;
    off += (bytes + 255) & ~(size_t)255;
    return p;
  };
  int* deg = (int*)take((size_t)N_NODES * 4);
  int* rpart = (int*)take((size_t)N_NODES * 4);
  int* cursor = (int*)take((size_t)N_NODES * 4);
  int2* csr = (int2*)take((size_t)E_EDGES * 8);
  int* sel = (int*)take((size_t)NPERMS * N_NODES * KARY * 4);
  int* lens = (int*)take((size_t)N_NODES * 4);
  short* wihb = (short*)take((size_t)4 * F * F * 2);
  short* whb = (short*)take((size_t)4 * F * F * 2);
  short* wobT = (short*)take((size_t)NOUT * 2 * F * 2);
  float4* bq = (float4*)take((size_t)F * 16);
  ushort4* xgq = (ushort4*)take((size_t)N_NODES * F * 8);
  int* bsum = (int*)take(128 * 4);
  int* boff = (int*)take(128 * 4);
  (void)ws_size; (void)in_sizes; (void)n_in; (void)out_size;

  hipMemsetAsync(deg, 0, (size_t)N_NODES * 4, stream);
  hipMemsetAsync(cursor, 0, (size_t)N_NODES * 4, stream);

  k_hist_prepw<<<HIST_BLK + 256, 256, 0, stream>>>(adj, deg, w_ih, w_hh, b_ih, b_hh,
                                                   weight, wihb, whb, bq, wobT);
  k_scanA<<<98, 1024, 0, stream>>>(deg, rpart, bsum);
  k_scanB<<<1, 128, 0, stream>>>(bsum, boff);
  k_scatter<<<(E_EDGES + 255) / 256, 256, 0, stream>>>(adj, rpart, boff, cursor, csr);
  k_sel_xg<<<SEL_BLK + N_NODES / 32, 256, 0, stream>>>(csr, rpart, boff, deg, sel, lens,
                                                       feat, wihb, bq, xgq);
  k_lstm<<<N_NODES / LB, 512, 0, stream>>>(whb, xgq, sel, lens, feat, wobT, bias, out);
}

// Round 9
// 1115.044 us; speedup vs baseline: 1.3378x; 1.2155x over previous
//
#include <hip/hip_runtime.h>
#include <stdint.h>

#define N_NODES 100000
#define F 128
#define E_EDGES 1600000
#define KARY 8
#define NPERMS 4
#define NOUT 64

typedef __attribute__((ext_vector_type(8))) short bf16x8;
typedef __attribute__((ext_vector_type(4))) float f32x4;

// ---------------- threefry2x32 (JAX-exact, 20 rounds) ----------------
__device__ __forceinline__ uint32_t rotl32(uint32_t v, int r) {
  return (v << r) | (v >> (32 - r));
}
__device__ __forceinline__ void tf2x32(uint32_t k0, uint32_t k1, uint32_t& x0, uint32_t& x1) {
  uint32_t ks2 = k0 ^ k1 ^ 0x1BD11BDAu;
  x0 += k0; x1 += k1;
  x0 += x1; x1 = rotl32(x1,13); x1 ^= x0;
  x0 += x1; x1 = rotl32(x1,15); x1 ^= x0;
  x0 += x1; x1 = rotl32(x1,26); x1 ^= x0;
  x0 += x1; x1 = rotl32(x1, 6); x1 ^= x0;
  x0 += k1; x1 += ks2 + 1u;
  x0 += x1; x1 = rotl32(x1,17); x1 ^= x0;
  x0 += x1; x1 = rotl32(x1,29); x1 ^= x0;
  x0 += x1; x1 = rotl32(x1,16); x1 ^= x0;
  x0 += x1; x1 = rotl32(x1,24); x1 ^= x0;
  x0 += ks2; x1 += k0 + 2u;
  x0 += x1; x1 = rotl32(x1,13); x1 ^= x0;
  x0 += x1; x1 = rotl32(x1,15); x1 ^= x0;
  x0 += x1; x1 = rotl32(x1,26); x1 ^= x0;
  x0 += x1; x1 = rotl32(x1, 6); x1 ^= x0;
  x0 += k0; x1 += k1 + 3u;
  x0 += x1; x1 = rotl32(x1,17); x1 ^= x0;
  x0 += x1; x1 = rotl32(x1,29); x1 ^= x0;
  x0 += x1; x1 = rotl32(x1,16); x1 ^= x0;
  x0 += x1; x1 = rotl32(x1,24); x1 ^= x0;
  x0 += k1; x1 += ks2 + 4u;
  x0 += x1; x1 = rotl32(x1,13); x1 ^= x0;
  x0 += x1; x1 = rotl32(x1,15); x1 ^= x0;
  x0 += x1; x1 = rotl32(x1,26); x1 ^= x0;
  x0 += x1; x1 = rotl32(x1, 6); x1 ^= x0;
  x0 += ks2; x1 += k0 + 5u;
}

// bf16 helpers
__device__ __forceinline__ unsigned short f2bf(float f) {  // RNE
  uint32_t u = __float_as_uint(f);
  uint32_t r = (u + 0x7FFFu + ((u >> 16) & 1u)) >> 16;
  return (unsigned short)r;
}
__device__ __forceinline__ float ubf(uint32_t u) { return __uint_as_float(u); }
// packed f32->bf16 (RNE) -- one instr for two converts
__device__ __forceinline__ uint32_t cvtpk(float lo, float hi) {
  uint32_t r;
  asm("v_cvt_pk_bf16_f32 %0, %1, %2" : "=v"(r) : "v"(lo), "v"(hi));
  return r;
}

// native transcendentals: single v_exp_f32 / v_rcp_f32.
__device__ __forceinline__ f32x4 exp2v(f32x4 x) {
  f32x4 r;
  r.x = __builtin_amdgcn_exp2f(x.x);
  r.y = __builtin_amdgcn_exp2f(x.y);
  r.z = __builtin_amdgcn_exp2f(x.z);
  r.w = __builtin_amdgcn_exp2f(x.w);
  return r;
}
__device__ __forceinline__ f32x4 rcpv(f32x4 x) {
  f32x4 r;
  r.x = __builtin_amdgcn_rcpf(x.x);
  r.y = __builtin_amdgcn_rcpf(x.y);
  r.z = __builtin_amdgcn_rcpf(x.z);
  r.w = __builtin_amdgcn_rcpf(x.w);
  return r;
}
// PRE-SCALED gate forms. i/f/o rows carry -log2(e): sigmoid(z)=rcp(1+exp2(y)).
// g rows carry +2*log2(e): tanh(z) = 1 - 2*rcp(exp2(y)+1) -- no mul at all.
__device__ __forceinline__ f32x4 sig4p(f32x4 y) {
  return rcpv(1.0f + exp2v(y));
}
__device__ __forceinline__ f32x4 tanh4p2(f32x4 y) {
  return 1.0f - 2.0f * rcpv(exp2v(y) + 1.0f);
}
// unscaled tanh, used for tanh(c_n)
__device__ __forceinline__ f32x4 tanh4(f32x4 x) {
  return 1.0f - 2.0f * rcpv(exp2v(x * 2.88539008f) + 1.0f);
}
__device__ __forceinline__ float sigf(float x) {
  return __builtin_amdgcn_rcpf(1.0f + __builtin_amdgcn_exp2f(x * -1.44269504f));
}

#define GSC -1.44269504f   // -log2(e): pre-scale for i/f/o gate rows
#define GSC_G 2.88539008f  // +2*log2(e): pre-scale for g gate rows

// ---------------- CSR build ----------------
#define HIST_BLK (E_EDGES / 256)  // 6250

// fat kernel: histogram (blocks 0..6249) + weight prep (next 256 blocks)
// NOTE: wihb/whb/bq are PRE-SCALED per gate row block (see sig4p/tanh4p2);
// wobT/bias are not.
__global__ __launch_bounds__(256) void k_hist_prepw(
    const int2* __restrict__ adj, int* __restrict__ deg,
    const float* __restrict__ w_ih, const float* __restrict__ w_hh,
    const float* __restrict__ b_ih, const float* __restrict__ b_hh,
    const float* __restrict__ weight,
    short* __restrict__ wihb, short* __restrict__ whb,
    float4* __restrict__ bq, short* __restrict__ wobT) {
  int b = blockIdx.x;
  if (b < HIST_BLK) {
    int e = b * 256 + threadIdx.x;
    atomicAdd(&deg[adj[e].x], 1);
  } else {
    int t = (b - HIST_BLK) * 256 + threadIdx.x;  // 0 .. 65535
    float sc = ((t >> 14) == 2) ? GSC_G : GSC;   // row = t>>7, gate = row>>7
    wihb[t] = (short)f2bf(w_ih[t] * sc);
    whb[t] = (short)f2bf(w_hh[t] * sc);
    if (t < 2 * F * NOUT) {
      int n = t & 63, k = t >> 6;
      wobT[n * 256 + k] = (short)f2bf(weight[k * NOUT + n]);
    }
    if (t < F)
      bq[t] = make_float4(GSC * (b_ih[t] + b_hh[t]), GSC * (b_ih[F + t] + b_hh[F + t]),
                          GSC_G * (b_ih[2 * F + t] + b_hh[2 * F + t]),
                          GSC * (b_ih[3 * F + t] + b_hh[3 * F + t]));
  }
}

// ---------- coalesced 3-phase exclusive scan ----------
__global__ __launch_bounds__(1024) void k_scanA(const int* __restrict__ deg,
                                                int* __restrict__ rpart,
                                                int* __restrict__ bsum) {
  __shared__ int s[1024];
  int tid = threadIdx.x;
  int i = blockIdx.x * 1024 + tid;
  int v = (i < N_NODES) ? deg[i] : 0;
  s[tid] = v;
  __syncthreads();
  for (int off = 1; off < 1024; off <<= 1) {
    int t = (tid >= off) ? s[tid - off] : 0;
    __syncthreads();
    s[tid] += t;
    __syncthreads();
  }
  if (i < N_NODES) rpart[i] = s[tid] - v;  // block-local exclusive
  if (tid == 1023) bsum[blockIdx.x] = s[tid];
}

__global__ __launch_bounds__(128) void k_scanB(const int* __restrict__ bsum,
                                               int* __restrict__ boff) {
  __shared__ int s[128];
  int tid = threadIdx.x;
  int v = (tid < 98) ? bsum[tid] : 0;
  s[tid] = v;
  __syncthreads();
  for (int off = 1; off < 128; off <<= 1) {
    int t = (tid >= off) ? s[tid - off] : 0;
    __syncthreads();
    s[tid] += t;
    __syncthreads();
  }
  if (tid < 98) boff[tid] = s[tid] - v;  // exclusive over block sums
}

__global__ void k_scatter(const int2* __restrict__ adj, const int* __restrict__ rpart,
                          const int* __restrict__ boff, int* __restrict__ cursor,
                          int2* __restrict__ csr) {
  int e = blockIdx.x * blockDim.x + threadIdx.x;
  if (e < E_EDGES) {
    int2 a = adj[e];
    int pos = rpart[a.x] + boff[a.x >> 10] + atomicAdd(&cursor[a.x], 1);
    csr[pos] = make_int2(a.y, e);  // (dst, edge_id)
  }
}

#define HS_LD 136  // 128 + 8 pad shorts
#define SEL_BLK ((N_NODES + 255) / 256)  // 391

// fat kernel: top-8 selection (blocks 0..390, latency/VALU-bound) overlapped
// with x-side-gates MFMA GEMM (remaining 3125 blocks, memory/MFMA-bound).
// xgq uses the PAIRED layout (R5): feature fi -> slot (fi&15)+16*(fi>>5),
// halves ft = bit4; k_lstm reads ONE aligned 16B uint4 per (node, lane).
__global__ __launch_bounds__(256) void k_sel_xg(
    const int2* __restrict__ csr, const int* __restrict__ rpart,
    const int* __restrict__ boff,
    const int* __restrict__ deg, int* __restrict__ sel, int* __restrict__ lens,
    const float* __restrict__ feat, const short* __restrict__ wihb,
    const float4* __restrict__ bq, ushort4* __restrict__ xgq) {
  __shared__ short as_[32 * HS_LD];
  if (blockIdx.x < SEL_BLK) {
    // ---------------- selection (4 perms fused, JAX lexsort-exact) ----------
    int n = blockIdx.x * 256 + threadIdx.x;
    if (n >= N_NODES) return;
    uint32_t pk0[NPERMS], pk1[NPERMS];
#pragma unroll
    for (int p = 0; p < NPERMS; ++p) {
      uint32_t a = 0u, b = (uint32_t)p;
      tf2x32(0u, 42u, a, b);
      pk0[p] = a; pk1[p] = b;
    }
    int off = rpart[n] + boff[n >> 10], d = deg[n];
    unsigned long long key[NPERMS][KARY];
    int nbr[NPERMS][KARY];
#pragma unroll
    for (int p = 0; p < NPERMS; ++p)
#pragma unroll
      for (int i = 0; i < KARY; ++i) { key[p][i] = ~0ULL; nbr[p][i] = -1; }
    for (int e = 0; e < d; ++e) {
      int2 ent = csr[off + e];
#pragma unroll
      for (int p = 0; p < NPERMS; ++p) {
        uint32_t x0 = 0u, x1 = (uint32_t)ent.y;
        tf2x32(pk0[p], pk1[p], x0, x1);
        uint32_t bits = x0 ^ x1;
        unsigned long long k = ((unsigned long long)(bits >> 9) << 21) | (unsigned)ent.y;
        if (k < key[p][KARY - 1]) {
          key[p][KARY - 1] = k; nbr[p][KARY - 1] = ent.x;
#pragma unroll
          for (int s = KARY - 1; s >= 1; --s) {
            if (key[p][s] < key[p][s - 1]) {
              unsigned long long tk = key[p][s]; key[p][s] = key[p][s - 1]; key[p][s - 1] = tk;
              int tn = nbr[p][s]; nbr[p][s] = nbr[p][s - 1]; nbr[p][s - 1] = tn;
            }
          }
        }
      }
    }
    int L = d < KARY ? d : KARY;
    lens[n] = L;
#pragma unroll
    for (int p = 0; p < NPERMS; ++p)
#pragma unroll
      for (int t = 0; t < KARY; ++t)
        sel[((size_t)p * N_NODES + n) * KARY + t] = (t < L) ? nbr[p][t] : -1;
  } else {
    // ---------------- x-side gates via MFMA: 32 nodes/block ----------------
    const int tid = threadIdx.x;
    const int w = tid >> 6, l = tid & 63;
    const int l15 = l & 15, q = l >> 4;
    const int nb = (blockIdx.x - SEL_BLK) * 32;
#pragma unroll
    for (int i = 0; i < 4; ++i) {
      int idx = tid + i * 256;  // 1024 float4 = 32 rows x 128 cols
      int row = idx >> 5, c4 = (idx & 31) * 4;
      float4 v = *(const float4*)&feat[(size_t)(nb + row) * F + c4];
      ushort4 s;
      s.x = f2bf(v.x); s.y = f2bf(v.y); s.z = f2bf(v.z); s.w = f2bf(v.w);
      *(ushort4*)&as_[row * HS_LD + c4] = s;
    }
    __syncthreads();

    f32x4 acc[2][2][4];
#pragma unroll
    for (int mt = 0; mt < 2; ++mt)
#pragma unroll
      for (int ft = 0; ft < 2; ++ft)
#pragma unroll
        for (int g4 = 0; g4 < 4; ++g4) acc[mt][ft][g4] = (f32x4){0.f, 0.f, 0.f, 0.f};

    const short* ab = as_ + l15 * HS_LD + q * 8;
#pragma unroll
    for (int kt = 0; kt < 4; ++kt) {
      bf16x8 a0 = *(const bf16x8*)(ab + kt * 32);
      bf16x8 a1 = *(const bf16x8*)(ab + 16 * HS_LD + kt * 32);
#pragma unroll
      for (int g4 = 0; g4 < 4; ++g4)
#pragma unroll
        for (int ft = 0; ft < 2; ++ft) {
          bf16x8 b = *(const bf16x8*)(wihb + (size_t)(g4 * 128 + 16 * ft + 32 * w + l15) * F + q * 8 + kt * 32);
          acc[0][ft][g4] = __builtin_amdgcn_mfma_f32_16x16x32_bf16(a0, b, acc[0][ft][g4], 0, 0, 0);
          acc[1][ft][g4] = __builtin_amdgcn_mfma_f32_16x16x32_bf16(a1, b, acc[1][ft][g4], 0, 0, 0);
        }
    }
#pragma unroll
    for (int mt = 0; mt < 2; ++mt)
#pragma unroll
      for (int ft = 0; ft < 2; ++ft) {
        int fi = 32 * w + 16 * ft + l15;
        float4 bb = bq[fi];
#pragma unroll
        for (int r = 0; r < 4; ++r) {
          int node = nb + mt * 16 + q * 4 + r;
          ushort4 o;
          o.x = f2bf(acc[mt][ft][0][r] + bb.x);
          o.y = f2bf(acc[mt][ft][1][r] + bb.y);
          o.z = f2bf(acc[mt][ft][2][r] + bb.z);
          o.w = f2bf(acc[mt][ft][3][r] + bb.w);
          // paired layout: slot (l15 + 16w) holds (ft=0 | ft=1) as 16B
          xgq[(size_t)node * F + (l15 + 16 * w) * 2 + ft] = o;
        }
      }
  }
}

// ---------------- fused LSTM via MFMA + fused head ----------------
// R9 = R5 exact structure (926 us verified) + algebraically-dead work cuts:
// (1) t=0: h0=0 so acc = x-gates exactly -> skip the whole MFMA phase, the
//     hs read, and the f-gate sigmoid (ff*c0 = 0).
// (2) t=7: o-gate/tanh/h-write and end-of-step barrier dropped (h7 dead --
//     the head uses cst only; t=7 reads hs[1], head stages into hs[0]).
// (3) hs zero-init dropped: t=0 never reads hs; for t>=1 unwritten rows
//     (len=0 / frozen) only feed their OWN discarded gates (rows are
//     independent through the GEMM -- the R1 invariant).
#define LB 8
#define OS_LD 264
__global__ __launch_bounds__(256, 2) void k_lstm(const short* __restrict__ whb,
                                                 const ushort4* __restrict__ xgq,
                                                 const int* __restrict__ sel,
                                                 const int* __restrict__ lens,
                                                 const float* __restrict__ feat,
                                                 const short* __restrict__ wobT,
                                                 const float* __restrict__ bias,
                                                 float* __restrict__ out) {
  __shared__ short hs[2][32 * HS_LD];  // 17408 B; hs[0] reused for the head
  __shared__ int sel_l[32][9];
  const int tid = threadIdx.x;
  const int w = tid >> 6;
  const int l = tid & 63;
  const int l15 = l & 15, q = l >> 4;
  const int nb = blockIdx.x * LB;
  const char* xgb = (const char*)xgq;
  const int fi16 = (16 * w + l15) * 16;  // byte offset of this lane's 16B pair

  {
    int m = tid >> 3, t = tid & 7;
    int node = nb + (m >> 2), p = m & 3;
    sel_l[m][t] = sel[((size_t)p * N_NODES + node) * KARY + t];
  }
  uint32_t lp = 0;
#pragma unroll
  for (int i = 0; i < 8; ++i) lp |= (uint32_t)lens[nb + i] << (4 * i);

  // persistent B: breg[kt][g4][ft]  (128 VGPRs)
  bf16x8 breg[4][4][2];
#pragma unroll
  for (int kt = 0; kt < 4; ++kt)
#pragma unroll
    for (int g4 = 0; g4 < 4; ++g4)
#pragma unroll
      for (int ft = 0; ft < 2; ++ft)
        breg[kt][g4][ft] = *(const bf16x8*)(whb + (size_t)(g4 * 128 + 16 * ft + 32 * w + l15) * F + q * 8 + kt * 32);

  const short* ab0 = hs[0] + l15 * HS_LD + q * 8;
  const short* ab1 = hs[1] + l15 * HS_LD + q * 8;

  f32x4 cst[2][2];
#pragma unroll
  for (int mt = 0; mt < 2; ++mt)
#pragma unroll
    for (int ft = 0; ft < 2; ++ft) cst[mt][ft] = (f32x4){0.f, 0.f, 0.f, 0.f};

  __syncthreads();  // sel_l ready

  // gather this step's paired xg quads into acc (MFMA C-input fold)
  auto gather_acc = [&](int t, f32x4 (&acc)[2][2][4]) {
    uint4 xr[2][4];
#pragma unroll
    for (int mt = 0; mt < 2; ++mt)
#pragma unroll
      for (int r = 0; r < 4; ++r) {
        int seq = mt * 16 + q * 4 + r;
        int v = sel_l[seq][t];
        v = v < 0 ? 0 : v;
        xr[mt][r] = *(const uint4*)(xgb + (v << 10) + fi16);
      }
#pragma unroll
    for (int mt = 0; mt < 2; ++mt)
#pragma unroll
      for (int r = 0; r < 4; ++r) {
        uint4 x = xr[mt][r];
        acc[mt][0][0][r] = ubf(x.x << 16);
        acc[mt][0][1][r] = ubf(x.x & 0xffff0000u);
        acc[mt][0][2][r] = ubf(x.y << 16);
        acc[mt][0][3][r] = ubf(x.y & 0xffff0000u);
        acc[mt][1][0][r] = ubf(x.z << 16);
        acc[mt][1][1][r] = ubf(x.z & 0xffff0000u);
        acc[mt][1][2][r] = ubf(x.w << 16);
        acc[mt][1][3][r] = ubf(x.w & 0xffff0000u);
      }
  };

  auto write_h = [&](int t, short* hw, int mt, int ft, f32x4 oo, f32x4 cn) {
    f32x4 hh = oo * tanh4(cn);
    int base = (mt * 16 + q * 4) * HS_LD + 32 * w + 16 * ft + l15;
    uint32_t p01 = cvtpk(hh[0], hh[1]);
    uint32_t p23 = cvtpk(hh[2], hh[3]);
    hw[base + 0 * HS_LD] = (short)p01;
    hw[base + 1 * HS_LD] = (short)(p01 >> 16);
    hw[base + 2 * HS_LD] = (short)p23;
    hw[base + 3 * HS_LD] = (short)(p23 >> 16);
  };

  // ---------------- t = 0 special: h0 = 0 -> gates = x-gates, no MFMA ------
  {
    f32x4 acc[2][2][4];
    gather_acc(0, acc);
#pragma unroll
    for (int mt = 0; mt < 2; ++mt) {
      int len = (lp >> (4 * (mt * 4 + q))) & 15;
      bool live = 0 < len;
#pragma unroll
      for (int ft = 0; ft < 2; ++ft) {
        f32x4 ii = sig4p(acc[mt][ft][0]);
        f32x4 gg = tanh4p2(acc[mt][ft][2]);
        f32x4 cn = ii * gg;  // ff * c0 = 0
        if (live) {
          cst[mt][ft] = cn;
          f32x4 oo = sig4p(acc[mt][ft][3]);
          write_h(0, hs[1], mt, ft, oo, cn);
        }
      }
    }
    __syncthreads();
  }

  // ---------------- t = 1..6: full steps ----------------
  auto lstm_step = [&](int t, const short* abase, short* hw) {
    f32x4 acc[2][2][4];
    gather_acc(t, acc);
#pragma unroll
    for (int kt = 0; kt < 4; ++kt) {
      bf16x8 a0 = *(const bf16x8*)(abase + 0 * 16 * HS_LD + kt * 32);
      bf16x8 a1 = *(const bf16x8*)(abase + 1 * 16 * HS_LD + kt * 32);
#pragma unroll
      for (int g4 = 0; g4 < 4; ++g4)
#pragma unroll
        for (int ft = 0; ft < 2; ++ft) {
          acc[0][ft][g4] = __builtin_amdgcn_mfma_f32_16x16x32_bf16(a0, breg[kt][g4][ft], acc[0][ft][g4], 0, 0, 0);
          acc[1][ft][g4] = __builtin_amdgcn_mfma_f32_16x16x32_bf16(a1, breg[kt][g4][ft], acc[1][ft][g4], 0, 0, 0);
        }
    }
    // NO mid barrier: epilogue writes go to the OTHER buffer (hw).
#pragma unroll
    for (int mt = 0; mt < 2; ++mt) {
      int len = (lp >> (4 * (mt * 4 + q))) & 15;
      bool live = t < len;
#pragma unroll
      for (int ft = 0; ft < 2; ++ft) {
        f32x4 ii = sig4p(acc[mt][ft][0]);
        f32x4 ff = sig4p(acc[mt][ft][1]);
        f32x4 gg = tanh4p2(acc[mt][ft][2]);
        f32x4 cn = ff * cst[mt][ft] + ii * gg;
        if (live) {
          cst[mt][ft] = cn;
          f32x4 oo = sig4p(acc[mt][ft][3]);
          write_h(t, hw, mt, ft, oo, cn);
        }
      }
    }
    __syncthreads();  // writes(t) visible before reads(t+1); ONE barrier/step
  };

  lstm_step(1, ab1, hs[0]);
  lstm_step(2, ab0, hs[1]);
  lstm_step(3, ab1, hs[0]);
  lstm_step(4, ab0, hs[1]);
  lstm_step(5, ab1, hs[0]);
  lstm_step(6, ab0, hs[1]);

  // ---------------- t = 7 final: cst update only (h7 dead, no barrier) -----
  {
    f32x4 acc[2][2][4];
    gather_acc(7, acc);
#pragma unroll
    for (int kt = 0; kt < 4; ++kt) {
      bf16x8 a0 = *(const bf16x8*)(ab1 + 0 * 16 * HS_LD + kt * 32);
      bf16x8 a1 = *(const bf16x8*)(ab1 + 1 * 16 * HS_LD + kt * 32);
#pragma unroll
      for (int g4 = 0; g4 < 4; ++g4)
#pragma unroll
        for (int ft = 0; ft < 2; ++ft) {
          acc[0][ft][g4] = __builtin_amdgcn_mfma_f32_16x16x32_bf16(a0, breg[kt][g4][ft], acc[0][ft][g4], 0, 0, 0);
          acc[1][ft][g4] = __builtin_amdgcn_mfma_f32_16x16x32_bf16(a1, breg[kt][g4][ft], acc[1][ft][g4], 0, 0, 0);
        }
    }
#pragma unroll
    for (int mt = 0; mt < 2; ++mt) {
      int len = (lp >> (4 * (mt * 4 + q))) & 15;
      bool live = 7 < len;
#pragma unroll
      for (int ft = 0; ft < 2; ++ft) {
        f32x4 ii = sig4p(acc[mt][ft][0]);
        f32x4 ff = sig4p(acc[mt][ft][1]);
        f32x4 gg = tanh4p2(acc[mt][ft][2]);
        f32x4 cn = ff * cst[mt][ft] + ii * gg;
        if (live) cst[mt][ft] = cn;
      }
    }
    // no barrier: t=7 read hs[1]; head staging below writes hs[0] (disjoint)
  }

  // ================= fused head: out[8][64] = sig([feat|hn]@W + b) =========
  short* as2 = hs[0];  // reinterpret as [16][OS_LD]; 16*264*2 = 8448 B fits

  // stage hn (from cst) into cols 128..255 of rows 0..7
#pragma unroll
  for (int mt = 0; mt < 2; ++mt)
#pragma unroll
    for (int ft = 0; ft < 2; ++ft) {
      f32x4 cc = cst[mt][ft];
      float hv = (cc.x + cc.y + cc.z + cc.w) * 0.25f;
      as2[(mt * 4 + q) * OS_LD + 128 + 32 * w + 16 * ft + l15] = (short)f2bf(hv);
    }
  // stage feat bf16 into cols 0..127 of rows 0..7 (8x128 = 256 float4)
  {
    int row = tid >> 5, c4 = (tid & 31) * 4;
    float4 v = *(const float4*)&feat[(size_t)(nb + row) * F + c4];
    ushort4 s;
    s.x = f2bf(v.x); s.y = f2bf(v.y); s.z = f2bf(v.z); s.w = f2bf(v.w);
    *(ushort4*)&as2[row * OS_LD + c4] = s;
  }
  float bb = bias[16 * w + l15];
  __syncthreads();

  // wave w computes out cols [16w,16w+16): 8 MFMA over K=256
  f32x4 oacc = (f32x4){0.f, 0.f, 0.f, 0.f};
  const short* ab2 = as2 + l15 * OS_LD + q * 8;
#pragma unroll
  for (int kt = 0; kt < 8; ++kt) {
    bf16x8 a = *(const bf16x8*)(ab2 + kt * 32);  // rows 8-15 garbage, discarded
    bf16x8 b = *(const bf16x8*)(wobT + (size_t)(16 * w + l15) * 256 + q * 8 + kt * 32);
    oacc = __builtin_amdgcn_mfma_f32_16x16x32_bf16(a, b, oacc, 0, 0, 0);
  }
  if (q < 2) {  // C rows q*4+r in 0..7 are the valid nodes
#pragma unroll
    for (int r = 0; r < 4; ++r) {
      int node = nb + q * 4 + r;
      out[(size_t)node * NOUT + 16 * w + l15] = sigf(oacc[r] + bb);
    }
  }
}

extern "C" void kernel_launch(void* const* d_in, const int* in_sizes, int n_in,
                              void* d_out, int out_size, void* d_ws, size_t ws_size,
                              hipStream_t stream) {
  const float* feat = (const float*)d_in[0];
  const int2* adj = (const int2*)d_in[1];
  const float* w_ih = (const float*)d_in[2];
  const float* w_hh = (const float*)d_in[3];
  const float* b_ih = (const float*)d_in[4];
  const float* b_hh = (const float*)d_in[5];
  const float* weight = (const float*)d_in[6];
  const float* bias = (const float*)d_in[7];
  float* out = (float*)d_out;

  size_t off = 0;
  auto take = [&](size_t bytes) -> void* {
    void* p = (char*)d_ws + off;
    off += (bytes + 255) & ~(size_t)255;
    return p;
  };
  int* deg = (int*)take((size_t)N_NODES * 4);
  int* rpart = (int*)take((size_t)N_NODES * 4);
  int* cursor = (int*)take((size_t)N_NODES * 4);
  int2* csr = (int2*)take((size_t)E_EDGES * 8);
  int* sel = (int*)take((size_t)NPERMS * N_NODES * KARY * 4);
  int* lens = (int*)take((size_t)N_NODES * 4);
  short* wihb = (short*)take((size_t)4 * F * F * 2);
  short* whb = (short*)take((size_t)4 * F * F * 2);
  short* wobT = (short*)take((size_t)NOUT * 2 * F * 2);
  float4* bq = (float4*)take((size_t)F * 16);
  ushort4* xgq = (ushort4*)take((size_t)N_NODES * F * 8);
  int* bsum = (int*)take(128 * 4);
  int* boff = (int*)take(128 * 4);
  (void)ws_size; (void)in_sizes; (void)n_in; (void)out_size;

  hipMemsetAsync(deg, 0, (size_t)N_NODES * 4, stream);
  hipMemsetAsync(cursor, 0, (size_t)N_NODES * 4, stream);

  k_hist_prepw<<<HIST_BLK + 256, 256, 0, stream>>>(adj, deg, w_ih, w_hh, b_ih, b_hh,
                                                   weight, wihb, whb, bq, wobT);
  k_scanA<<<98, 1024, 0, stream>>>(deg, rpart, bsum);
  k_scanB<<<1, 128, 0, stream>>>(bsum, boff);
  k_scatter<<<(E_EDGES + 255) / 256, 256, 0, stream>>>(adj, rpart, boff, cursor, csr);
  k_sel_xg<<<SEL_BLK + N_NODES / 32, 256, 0, stream>>>(csr, rpart, boff, deg, sel, lens,
                                                       feat, wihb, bq, xgq);
  k_lstm<<<N_NODES / LB, 256, 0, stream>>>(whb, xgq, sel, lens, feat, wobT, bias, out);
}